// Round 2
// baseline (491.680 us; speedup 1.0000x reference)
//
#include <hip/hip_runtime.h>

#define BATCH 64
#define SEQ   4096
#define DECD  512
#define ENC   256
#define TS    128                // rows per block (8 waves x 16 rows)
#define NCHUNK (SEQ / TS)        // 32 chunks per batch
#define OUT_ATTN (BATCH * ENC)   // offset of attn region in d_out

typedef short  short8  __attribute__((ext_vector_type(8)));
typedef float  floatx4 __attribute__((ext_vector_type(4)));

__device__ __forceinline__ short f2bf(float f) {
    union { float f; unsigned u; } v; v.f = f;
    unsigned u = v.u;
    u += 0x7FFFu + ((u >> 16) & 1u);
    return (short)(u >> 16);
}

__device__ __forceinline__ float bf2f(short s) {
    union { unsigned u; float f; } v;
    v.u = ((unsigned)(unsigned short)s) << 16;
    return v.f;
}

__device__ __forceinline__ float fast_tanh(float x) {
    x = fminf(fmaxf(x, -9.0f), 9.0f);
    float e2 = __expf(2.0f * x);
    float r  = __builtin_amdgcn_rcpf(e2 + 1.0f);
    return fmaf(-2.0f, r, 1.0f);
}

// async global->LDS, 16B per lane. LDS dest = wave-uniform base + lane*16.
__device__ __forceinline__ void gload_lds16(const short* g, short* l) {
    __builtin_amdgcn_global_load_lds(
        (const __attribute__((address_space(1))) unsigned int*)g,
        (__attribute__((address_space(3))) unsigned int*)l,
        16, 0, 0);
}

// Kernel 1 (merged): blocks [0,256): dp split-K x4; blocks [256,288): pack We.
__global__ void prep_kernel(const float* __restrict__ dh,
                            const float* __restrict__ Wd,
                            const float* __restrict__ bd,
                            const float* __restrict__ be,
                            const float* __restrict__ We,
                            float* __restrict__ dpb4,
                            short* __restrict__ WeF) {
    __shared__ float dhs[128];
    int blk = blockIdx.x;
    int t = threadIdx.x;
    if (blk < 256) {
        // dpb4[(b*4+j)][e] = partial sum (+ bd+be on j==0)
        int b = blk >> 2, j = blk & 3;
        if (t < 128) dhs[t] = dh[b * DECD + j * 128 + t];
        __syncthreads();
        const float* wp = Wd + (size_t)(j * 128) * ENC + t;
        float a0 = 0.f, a1 = 0.f, a2 = 0.f, a3 = 0.f;
#pragma unroll 4
        for (int d = 0; d < 128; d += 4) {
            a0 = fmaf(dhs[d],     wp[(size_t)(d)     * ENC], a0);
            a1 = fmaf(dhs[d + 1], wp[(size_t)(d + 1) * ENC], a1);
            a2 = fmaf(dhs[d + 2], wp[(size_t)(d + 2) * ENC], a2);
            a3 = fmaf(dhs[d + 3], wp[(size_t)(d + 3) * ENC], a3);
        }
        float r = (a0 + a1) + (a2 + a3);
        if (j == 0) r += bd[t] + be[t];
        dpb4[(size_t)(b * 4 + j) * ENC + t] = r;
    } else {
        // pack We into bf16 MFMA B-fragment layout; each kt slice = 16KB contiguous
        int gid  = (blk - 256) * 256 + t;            // 0..8191
        int lane = gid & 63;
        int nt   = (gid >> 6) & 15;
        int kt   = gid >> 10;
        int quad = lane >> 4, l16 = lane & 15;
        int n = nt * 16 + l16;
        short8 v;
#pragma unroll
        for (int j = 0; j < 8; ++j) {
            int k = kt * 32 + quad * 8 + j;
            v[j] = f2bf(We[k * ENC + n]);
        }
        *(short8*)(WeF + gid * 8) = v;
    }
}

// Kernel 2 (main): block = (b, chunk of 128 rows); 8 waves, 1 M-tile/wave (acc=64).
// enc is read ONCE: bf16 A-fragments (af[8], 32 VGPRs) are kept live and reused
// for the context pass via in-register weighted reduce (shfl over the 16 rows).
__global__ __launch_bounds__(512, 4) void main_kernel(
    const float* __restrict__ enc, const int* __restrict__ mask,
    const short* __restrict__ WeF, const float* __restrict__ dpb4,
    const float* __restrict__ Wa, const float* __restrict__ ba,
    float* __restrict__ out, float* __restrict__ ctx_ws, float* __restrict__ ml_ws)
{
    __shared__ short Bs[32768];      // 64 KB: B phase buffer; overlaid by epilogue arrays
    float* F    = (float*)Bs;        // overlay (valid after K-loop):
    float* scF  = F;                 // [0,128)      scores
    float* wgtF = F + 128;           // [128,256)    weights
    float* dpbF = F + 256;           // [256,512)    dpb
    float* waF  = F + 512;           // [512,768)    Wa
    float* ctxF = F + 768;           // [768,2816)   per-wave ctx partials [8][256]

    int blk   = blockIdx.x;
    int b     = blk >> 5;            // / NCHUNK
    int chunk = blk & 31;
    int s_base = chunk * TS;
    int t    = threadIdx.x;
    int w    = t >> 6, lane = t & 63;
    int quad = lane >> 4, l16 = lane & 15;

    const float* encB = enc + (size_t)b * SEQ * ENC;
    int row = s_base + w * 16 + l16;
    const float* aRow = encB + (size_t)row * ENC + quad * 8;

    // ---- A tile: load f32 once, keep as bf16 fragments for MFMA + context ----
    short8 af[8];
#pragma unroll
    for (int kkt = 0; kkt < 4; ++kkt) {
        floatx4 q0 = *(const floatx4*)(aRow + kkt * 32);
        floatx4 q1 = *(const floatx4*)(aRow + kkt * 32 + 4);
        short8 a;
#pragma unroll
        for (int j = 0; j < 4; ++j) { a[j] = f2bf(q0[j]); a[j + 4] = f2bf(q1[j]); }
        af[kkt] = a;
    }

    // stage phase 0: WeF slices 0..3 (64KB). 8 rounds x 512 threads x 16B.
#pragma unroll
    for (int j = 0; j < 8; ++j) {
        int c = j * 8 + w;           // chunk 0..63, 512 shorts each
        gload_lds16(WeF + c * 512 + lane * 8, Bs + c * 512 + lane * 8);
    }

#pragma unroll
    for (int kkt = 4; kkt < 8; ++kkt) {
        floatx4 q0 = *(const floatx4*)(aRow + kkt * 32);
        floatx4 q1 = *(const floatx4*)(aRow + kkt * 32 + 4);
        short8 a;
#pragma unroll
        for (int j = 0; j < 4; ++j) { a[j] = f2bf(q0[j]); a[j + 4] = f2bf(q1[j]); }
        af[kkt] = a;
    }

    floatx4 acc[16];
#pragma unroll
    for (int nt = 0; nt < 16; ++nt) acc[nt] = (floatx4){0.f, 0.f, 0.f, 0.f};

    __syncthreads();

#pragma unroll
    for (int kkt = 0; kkt < 4; ++kkt) {
        const short* bp = Bs + kkt * 8192 + lane * 8;
#pragma unroll
        for (int ng = 0; ng < 4; ++ng) {
            short8 bf0 = *(const short8*)(bp + (ng * 4 + 0) * 512);
            short8 bf1 = *(const short8*)(bp + (ng * 4 + 1) * 512);
            short8 bf2 = *(const short8*)(bp + (ng * 4 + 2) * 512);
            short8 bf3 = *(const short8*)(bp + (ng * 4 + 3) * 512);
            acc[ng * 4 + 0] = __builtin_amdgcn_mfma_f32_16x16x32_bf16(af[kkt], bf0, acc[ng * 4 + 0], 0, 0, 0);
            acc[ng * 4 + 1] = __builtin_amdgcn_mfma_f32_16x16x32_bf16(af[kkt], bf1, acc[ng * 4 + 1], 0, 0, 0);
            acc[ng * 4 + 2] = __builtin_amdgcn_mfma_f32_16x16x32_bf16(af[kkt], bf2, acc[ng * 4 + 2], 0, 0, 0);
            acc[ng * 4 + 3] = __builtin_amdgcn_mfma_f32_16x16x32_bf16(af[kkt], bf3, acc[ng * 4 + 3], 0, 0, 0);
        }
    }

    __syncthreads();                  // all waves done reading phase-0 B
    // stage phase 1: WeF slices 4..7 into the same buffer
#pragma unroll
    for (int j = 0; j < 8; ++j) {
        int c = j * 8 + w;
        gload_lds16(WeF + 32768 + c * 512 + lane * 8, Bs + c * 512 + lane * 8);
    }
    __syncthreads();

#pragma unroll
    for (int kkt = 4; kkt < 8; ++kkt) {
        const short* bp = Bs + (kkt - 4) * 8192 + lane * 8;
#pragma unroll
        for (int ng = 0; ng < 4; ++ng) {
            short8 bf0 = *(const short8*)(bp + (ng * 4 + 0) * 512);
            short8 bf1 = *(const short8*)(bp + (ng * 4 + 1) * 512);
            short8 bf2 = *(const short8*)(bp + (ng * 4 + 2) * 512);
            short8 bf3 = *(const short8*)(bp + (ng * 4 + 3) * 512);
            acc[ng * 4 + 0] = __builtin_amdgcn_mfma_f32_16x16x32_bf16(af[kkt], bf0, acc[ng * 4 + 0], 0, 0, 0);
            acc[ng * 4 + 1] = __builtin_amdgcn_mfma_f32_16x16x32_bf16(af[kkt], bf1, acc[ng * 4 + 1], 0, 0, 0);
            acc[ng * 4 + 2] = __builtin_amdgcn_mfma_f32_16x16x32_bf16(af[kkt], bf2, acc[ng * 4 + 2], 0, 0, 0);
            acc[ng * 4 + 3] = __builtin_amdgcn_mfma_f32_16x16x32_bf16(af[kkt], bf3, acc[ng * 4 + 3], 0, 0, 0);
        }
    }

    __syncthreads();                  // B dead; overlay epilogue arrays
    if (t < 256) {
        const float* dp = dpb4 + (size_t)b * 4 * ENC;
        dpbF[t] = dp[t] + dp[ENC + t] + dp[2 * ENC + t] + dp[3 * ENC + t];
    } else {
        waF[t - 256] = Wa[t - 256];
    }
    __syncthreads();

    // score_row = ba + sum_n Wa[n]*tanh(P[row][n] + dpb[n])
    float ba0 = ba[0];
    float part[4] = {0.f, 0.f, 0.f, 0.f};
#pragma unroll
    for (int nt = 0; nt < 16; ++nt) {
        int n = nt * 16 + l16;
        float wa  = waF[n];
        float dpv = dpbF[n];
#pragma unroll
        for (int r = 0; r < 4; ++r)
            part[r] = fmaf(wa, fast_tanh(acc[nt][r] + dpv), part[r]);
    }
#pragma unroll
    for (int r = 0; r < 4; ++r) {
        float v = part[r];
        v += __shfl_xor(v, 1);
        v += __shfl_xor(v, 2);
        v += __shfl_xor(v, 4);
        v += __shfl_xor(v, 8);
        part[r] = v;
    }
    if (l16 == 0) {
        int idx0 = w * 16 + quad * 4;
        int s0 = s_base + idx0;
        const int4 mv = *(const int4*)(mask + b * SEQ + s0);
        int mvals[4] = {mv.x, mv.y, mv.z, mv.w};
#pragma unroll
        for (int r = 0; r < 4; ++r) {
            float scv = part[r] + ba0;
            if (mvals[r] == 0) scv = -1e10f;
            scF[idx0 + r] = scv;
            out[OUT_ATTN + (size_t)b * SEQ + s0 + r] = scv;   // raw; final normalizes
        }
    }
    __syncthreads();

    // block softmax over 128 scores (each wave redundantly, via shuffles)
    float v0 = scF[lane], v1 = scF[lane + 64];
    float m = fmaxf(v0, v1);
    m = fmaxf(m, __shfl_xor(m, 1));
    m = fmaxf(m, __shfl_xor(m, 2));
    m = fmaxf(m, __shfl_xor(m, 4));
    m = fmaxf(m, __shfl_xor(m, 8));
    m = fmaxf(m, __shfl_xor(m, 16));
    m = fmaxf(m, __shfl_xor(m, 32));
    float e0 = __expf(v0 - m), e1 = __expf(v1 - m);
    float l = e0 + e1;
    l += __shfl_xor(l, 1);
    l += __shfl_xor(l, 2);
    l += __shfl_xor(l, 4);
    l += __shfl_xor(l, 8);
    l += __shfl_xor(l, 16);
    l += __shfl_xor(l, 32);
    if (t < TS) wgtF[t] = __expf(scF[t] - m);
    __syncthreads();

    // ---- context partial from the bf16 A-fragments (NO second enc read) ----
    // lane (quad,l16) of wave w holds enc[row][kkt*32+quad*8+j]; weight by its
    // row's softmax weight, reduce over the 16 rows (l16 = lane bits 0..3).
    float wrow = wgtF[w * 16 + l16];
#pragma unroll
    for (int kkt = 0; kkt < 8; ++kkt) {
        float c[8];
#pragma unroll
        for (int j = 0; j < 8; ++j)
            c[j] = wrow * bf2f(af[kkt][j]);
#pragma unroll
        for (int j = 0; j < 8; ++j) {
            c[j] += __shfl_xor(c[j], 1);
            c[j] += __shfl_xor(c[j], 2);
            c[j] += __shfl_xor(c[j], 4);
            c[j] += __shfl_xor(c[j], 8);
        }
        if (l16 == 0) {
            floatx4 u0 = {c[0], c[1], c[2], c[3]};
            floatx4 u1 = {c[4], c[5], c[6], c[7]};
            *(floatx4*)(ctxF + w * 256 + kkt * 32 + quad * 8)     = u0;
            *(floatx4*)(ctxF + w * 256 + kkt * 32 + quad * 8 + 4) = u1;
        }
    }
    __syncthreads();

    int cidx = b * NCHUNK + chunk;
    if (t < 256) {
        float cx = 0.f;
#pragma unroll
        for (int w2 = 0; w2 < 8; ++w2) cx += ctxF[w2 * 256 + t];
        ctx_ws[(size_t)cidx * ENC + t] = cx;
    }
    if (t == 0) {
        ml_ws[cidx * 2]     = m;
        ml_ws[cidx * 2 + 1] = l;
    }
}

// Kernel 3: combine chunk partials per batch; finalize context and attn.
// 8 blocks per batch: each redundantly computes (m,L); block j==0 emits context;
// each block normalizes a 512-element attn slice (parallel, not 16-iter loop).
__global__ void final_kernel(const float* __restrict__ ctx_ws,
                             const float* __restrict__ ml_ws,
                             float* __restrict__ out) {
    int blk = blockIdx.x, b = blk >> 3, j = blk & 7;
    int t = threadIdx.x;
    float m = -3.4e38f;
    for (int c = 0; c < NCHUNK; ++c)
        m = fmaxf(m, ml_ws[(b * NCHUNK + c) * 2]);
    float L = 0.f;
    for (int c = 0; c < NCHUNK; ++c)
        L += ml_ws[(b * NCHUNK + c) * 2 + 1] * __expf(ml_ws[(b * NCHUNK + c) * 2] - m);
    float inv = 1.0f / L;

    if (j == 0) {
        float cx = 0.f;
        for (int c = 0; c < NCHUNK; ++c) {
            float sc_c = __expf(ml_ws[(b * NCHUNK + c) * 2] - m);
            cx += sc_c * ctx_ws[(size_t)(b * NCHUNK + c) * ENC + t];
        }
        out[b * ENC + t] = cx * inv;
    }

    size_t base = OUT_ATTN + (size_t)b * SEQ + j * 512;
    float r0 = out[base + t];
    float r1 = out[base + 256 + t];
    out[base + t]       = __expf(r0 - m) * inv;
    out[base + 256 + t] = __expf(r1 - m) * inv;
}

extern "C" void kernel_launch(void* const* d_in, const int* in_sizes, int n_in,
                              void* d_out, int out_size, void* d_ws, size_t ws_size,
                              hipStream_t stream) {
    const float* dh   = (const float*)d_in[0];
    const float* enc  = (const float*)d_in[1];
    const int*   mask = (const int*)d_in[2];
    const float* Wd   = (const float*)d_in[3];
    const float* bd   = (const float*)d_in[4];
    const float* We   = (const float*)d_in[5];
    const float* be   = (const float*)d_in[6];
    const float* Wa   = (const float*)d_in[7];
    const float* ba   = (const float*)d_in[8];
    float* out = (float*)d_out;

    // ws (floats): ctx_ws[64*32*256] | ml_ws[64*32*2] | dpb4[64*4*256] | WeF (bf16, 64K shorts)
    float* w      = (float*)d_ws;
    float* ctx_ws = w;
    float* ml_ws  = w + BATCH * NCHUNK * ENC;
    float* dpb4   = ml_ws + BATCH * NCHUNK * 2;
    short* WeF    = (short*)(dpb4 + BATCH * 4 * ENC);

    hipLaunchKernelGGL(prep_kernel,  dim3(256 + 32),       dim3(256), 0, stream,
                       dh, Wd, bd, be, We, dpb4, WeF);
    hipLaunchKernelGGL(main_kernel,  dim3(BATCH * NCHUNK), dim3(512), 0, stream,
                       enc, mask, WeF, dpb4, Wa, ba, out, ctx_ws, ml_ws);
    hipLaunchKernelGGL(final_kernel, dim3(BATCH * 8),      dim3(256), 0, stream,
                       ctx_ws, ml_ws, out);
}

// Round 3
// 442.598 us; speedup vs baseline: 1.1109x; 1.1109x over previous
//
#include <hip/hip_runtime.h>

#define BATCH 64
#define SEQ   4096
#define DECD  512
#define ENC   256
#define TS    64                 // rows per block (4 waves x 16 rows)
#define NCHUNK (SEQ / TS)        // 64 chunks per batch
#define OUT_ATTN (BATCH * ENC)   // offset of attn region in d_out

typedef short  short8  __attribute__((ext_vector_type(8)));
typedef float  floatx4 __attribute__((ext_vector_type(4)));

__device__ __forceinline__ short f2bf(float f) {
    union { float f; unsigned u; } v; v.f = f;
    unsigned u = v.u;
    u += 0x7FFFu + ((u >> 16) & 1u);
    return (short)(u >> 16);
}

__device__ __forceinline__ float bf2f(short s) {
    union { unsigned u; float f; } v;
    v.u = ((unsigned)(unsigned short)s) << 16;
    return v.f;
}

__device__ __forceinline__ float fast_tanh(float x) {
    x = fminf(fmaxf(x, -9.0f), 9.0f);
    float e2 = __expf(2.0f * x);
    float r  = __builtin_amdgcn_rcpf(e2 + 1.0f);
    return fmaf(-2.0f, r, 1.0f);
}

// async global->LDS, 16B per lane. LDS dest = wave-uniform base + lane*16.
__device__ __forceinline__ void gload_lds16(const short* g, short* l) {
    __builtin_amdgcn_global_load_lds(
        (const __attribute__((address_space(1))) unsigned int*)g,
        (__attribute__((address_space(3))) unsigned int*)l,
        16, 0, 0);
}

// Kernel 1 (merged): blocks [0,256): dp split-K x4; blocks [256,288): pack We.
__global__ void prep_kernel(const float* __restrict__ dh,
                            const float* __restrict__ Wd,
                            const float* __restrict__ bd,
                            const float* __restrict__ be,
                            const float* __restrict__ We,
                            float* __restrict__ dpb4,
                            short* __restrict__ WeF) {
    __shared__ float dhs[128];
    int blk = blockIdx.x;
    int t = threadIdx.x;
    if (blk < 256) {
        // dpb4[(b*4+j)][e] = partial sum (+ bd+be on j==0)
        int b = blk >> 2, j = blk & 3;
        if (t < 128) dhs[t] = dh[b * DECD + j * 128 + t];
        __syncthreads();
        const float* wp = Wd + (size_t)(j * 128) * ENC + t;
        float a0 = 0.f, a1 = 0.f, a2 = 0.f, a3 = 0.f;
#pragma unroll 4
        for (int d = 0; d < 128; d += 4) {
            a0 = fmaf(dhs[d],     wp[(size_t)(d)     * ENC], a0);
            a1 = fmaf(dhs[d + 1], wp[(size_t)(d + 1) * ENC], a1);
            a2 = fmaf(dhs[d + 2], wp[(size_t)(d + 2) * ENC], a2);
            a3 = fmaf(dhs[d + 3], wp[(size_t)(d + 3) * ENC], a3);
        }
        float r = (a0 + a1) + (a2 + a3);
        if (j == 0) r += bd[t] + be[t];
        dpb4[(size_t)(b * 4 + j) * ENC + t] = r;
    } else {
        // pack We into bf16 MFMA B-fragment layout; each kt slice = 16KB contiguous
        int gid  = (blk - 256) * 256 + t;            // 0..8191
        int lane = gid & 63;
        int nt   = (gid >> 6) & 15;
        int kt   = gid >> 10;
        int quad = lane >> 4, l16 = lane & 15;
        int n = nt * 16 + l16;
        short8 v;
#pragma unroll
        for (int j = 0; j < 8; ++j) {
            int k = kt * 32 + quad * 8 + j;
            v[j] = f2bf(We[k * ENC + n]);
        }
        *(short8*)(WeF + gid * 8) = v;
    }
}

// Kernel 2 (main): block = (b, chunk of 64 rows); 4 waves, 16 rows/wave.
// enc is read ONCE: bf16 A-fragments (af[8], 32 VGPRs) are kept live and reused
// for the context pass via in-register weighted reduce (shfl over the 16 rows).
// 256 threads + __launch_bounds__(256,2): 256-reg cap -> NO spills (round-2's
// 244 MB scratch writeback came from the 128-reg cap at (512,4)).
__global__ __launch_bounds__(256, 2) void main_kernel(
    const float* __restrict__ enc, const int* __restrict__ mask,
    const short* __restrict__ WeF, const float* __restrict__ dpb4,
    const float* __restrict__ Wa, const float* __restrict__ ba,
    float* __restrict__ out, float* __restrict__ ctx_ws, float* __restrict__ ml_ws)
{
    __shared__ short Bs[32768];      // 64 KB: B phase buffer; overlaid by epilogue arrays
    float* F    = (float*)Bs;        // overlay (valid after K-loop):
    float* scF  = F;                 // [0,64)       scores
    float* wgtF = F + 64;            // [64,128)     weights
    float* dpbF = F + 128;           // [128,384)    dpb
    float* waF  = F + 384;           // [384,640)    Wa
    float* ctxF = F + 640;           // [640,1664)   per-wave ctx partials [4][256]

    int blk   = blockIdx.x;
    int b     = blk >> 6;            // / NCHUNK
    int chunk = blk & 63;
    int s_base = chunk * TS;
    int t    = threadIdx.x;
    int w    = t >> 6, lane = t & 63;
    int quad = lane >> 4, l16 = lane & 15;

    const float* encB = enc + (size_t)b * SEQ * ENC;
    int row = s_base + w * 16 + l16;
    const float* aRow = encB + (size_t)row * ENC + quad * 8;

    // ---- A tile: load f32 once, keep as bf16 fragments for MFMA + context ----
    short8 af[8];
#pragma unroll
    for (int kkt = 0; kkt < 4; ++kkt) {
        floatx4 q0 = *(const floatx4*)(aRow + kkt * 32);
        floatx4 q1 = *(const floatx4*)(aRow + kkt * 32 + 4);
        short8 a;
#pragma unroll
        for (int j = 0; j < 4; ++j) { a[j] = f2bf(q0[j]); a[j + 4] = f2bf(q1[j]); }
        af[kkt] = a;
    }

    // stage phase 0: WeF slices 0..3 (64KB). 16 rounds x 256 threads x 16B.
#pragma unroll
    for (int j = 0; j < 16; ++j) {
        int c = j * 4 + w;           // chunk 0..63, 512 shorts each
        gload_lds16(WeF + c * 512 + lane * 8, Bs + c * 512 + lane * 8);
    }

#pragma unroll
    for (int kkt = 4; kkt < 8; ++kkt) {
        floatx4 q0 = *(const floatx4*)(aRow + kkt * 32);
        floatx4 q1 = *(const floatx4*)(aRow + kkt * 32 + 4);
        short8 a;
#pragma unroll
        for (int j = 0; j < 4; ++j) { a[j] = f2bf(q0[j]); a[j + 4] = f2bf(q1[j]); }
        af[kkt] = a;
    }

    floatx4 acc[16];
#pragma unroll
    for (int nt = 0; nt < 16; ++nt) acc[nt] = (floatx4){0.f, 0.f, 0.f, 0.f};

    __syncthreads();

#pragma unroll
    for (int kkt = 0; kkt < 4; ++kkt) {
        const short* bp = Bs + kkt * 8192 + lane * 8;
#pragma unroll
        for (int ng = 0; ng < 4; ++ng) {
            short8 bf0 = *(const short8*)(bp + (ng * 4 + 0) * 512);
            short8 bf1 = *(const short8*)(bp + (ng * 4 + 1) * 512);
            short8 bf2 = *(const short8*)(bp + (ng * 4 + 2) * 512);
            short8 bf3 = *(const short8*)(bp + (ng * 4 + 3) * 512);
            acc[ng * 4 + 0] = __builtin_amdgcn_mfma_f32_16x16x32_bf16(af[kkt], bf0, acc[ng * 4 + 0], 0, 0, 0);
            acc[ng * 4 + 1] = __builtin_amdgcn_mfma_f32_16x16x32_bf16(af[kkt], bf1, acc[ng * 4 + 1], 0, 0, 0);
            acc[ng * 4 + 2] = __builtin_amdgcn_mfma_f32_16x16x32_bf16(af[kkt], bf2, acc[ng * 4 + 2], 0, 0, 0);
            acc[ng * 4 + 3] = __builtin_amdgcn_mfma_f32_16x16x32_bf16(af[kkt], bf3, acc[ng * 4 + 3], 0, 0, 0);
        }
    }

    __syncthreads();                  // all waves done reading phase-0 B
    // stage phase 1: WeF slices 4..7 into the same buffer
#pragma unroll
    for (int j = 0; j < 16; ++j) {
        int c = j * 4 + w;
        gload_lds16(WeF + 32768 + c * 512 + lane * 8, Bs + c * 512 + lane * 8);
    }
    __syncthreads();

#pragma unroll
    for (int kkt = 4; kkt < 8; ++kkt) {
        const short* bp = Bs + (kkt - 4) * 8192 + lane * 8;
#pragma unroll
        for (int ng = 0; ng < 4; ++ng) {
            short8 bf0 = *(const short8*)(bp + (ng * 4 + 0) * 512);
            short8 bf1 = *(const short8*)(bp + (ng * 4 + 1) * 512);
            short8 bf2 = *(const short8*)(bp + (ng * 4 + 2) * 512);
            short8 bf3 = *(const short8*)(bp + (ng * 4 + 3) * 512);
            acc[ng * 4 + 0] = __builtin_amdgcn_mfma_f32_16x16x32_bf16(af[kkt], bf0, acc[ng * 4 + 0], 0, 0, 0);
            acc[ng * 4 + 1] = __builtin_amdgcn_mfma_f32_16x16x32_bf16(af[kkt], bf1, acc[ng * 4 + 1], 0, 0, 0);
            acc[ng * 4 + 2] = __builtin_amdgcn_mfma_f32_16x16x32_bf16(af[kkt], bf2, acc[ng * 4 + 2], 0, 0, 0);
            acc[ng * 4 + 3] = __builtin_amdgcn_mfma_f32_16x16x32_bf16(af[kkt], bf3, acc[ng * 4 + 3], 0, 0, 0);
        }
    }

    __syncthreads();                  // B dead; overlay epilogue arrays
    {
        const float* dp = dpb4 + (size_t)b * 4 * ENC;
        dpbF[t] = dp[t] + dp[ENC + t] + dp[2 * ENC + t] + dp[3 * ENC + t];
        waF[t]  = Wa[t];
    }
    __syncthreads();

    // score_row = ba + sum_n Wa[n]*tanh(P[row][n] + dpb[n])
    float ba0 = ba[0];
    float part[4] = {0.f, 0.f, 0.f, 0.f};
#pragma unroll
    for (int nt = 0; nt < 16; ++nt) {
        int n = nt * 16 + l16;
        float wa  = waF[n];
        float dpv = dpbF[n];
#pragma unroll
        for (int r = 0; r < 4; ++r)
            part[r] = fmaf(wa, fast_tanh(acc[nt][r] + dpv), part[r]);
    }
#pragma unroll
    for (int r = 0; r < 4; ++r) {
        float v = part[r];
        v += __shfl_xor(v, 1);
        v += __shfl_xor(v, 2);
        v += __shfl_xor(v, 4);
        v += __shfl_xor(v, 8);
        part[r] = v;
    }
    if (l16 == 0) {
        int idx0 = w * 16 + quad * 4;
        int s0 = s_base + idx0;
        const int4 mv = *(const int4*)(mask + b * SEQ + s0);
        int mvals[4] = {mv.x, mv.y, mv.z, mv.w};
#pragma unroll
        for (int r = 0; r < 4; ++r) {
            float scv = part[r] + ba0;
            if (mvals[r] == 0) scv = -1e10f;
            scF[idx0 + r] = scv;
            out[OUT_ATTN + (size_t)b * SEQ + s0 + r] = scv;   // raw; final normalizes
        }
    }
    __syncthreads();

    // block softmax over 64 scores (each wave redundantly, via shuffles)
    float v0 = scF[lane];
    float m = v0;
    m = fmaxf(m, __shfl_xor(m, 1));
    m = fmaxf(m, __shfl_xor(m, 2));
    m = fmaxf(m, __shfl_xor(m, 4));
    m = fmaxf(m, __shfl_xor(m, 8));
    m = fmaxf(m, __shfl_xor(m, 16));
    m = fmaxf(m, __shfl_xor(m, 32));
    float l = __expf(v0 - m);
    l += __shfl_xor(l, 1);
    l += __shfl_xor(l, 2);
    l += __shfl_xor(l, 4);
    l += __shfl_xor(l, 8);
    l += __shfl_xor(l, 16);
    l += __shfl_xor(l, 32);
    if (t < TS) wgtF[t] = __expf(scF[t] - m);
    __syncthreads();

    // ---- context partial from the bf16 A-fragments (NO second enc read) ----
    // lane (quad,l16) of wave w holds enc[row][kkt*32+quad*8+j]; weight by its
    // row's softmax weight, reduce over the 16 rows (l16 = lane bits 0..3).
    float wrow = wgtF[w * 16 + l16];
#pragma unroll
    for (int kkt = 0; kkt < 8; ++kkt) {
        float c[8];
#pragma unroll
        for (int j = 0; j < 8; ++j)
            c[j] = wrow * bf2f(af[kkt][j]);
#pragma unroll
        for (int j = 0; j < 8; ++j) {
            c[j] += __shfl_xor(c[j], 1);
            c[j] += __shfl_xor(c[j], 2);
            c[j] += __shfl_xor(c[j], 4);
            c[j] += __shfl_xor(c[j], 8);
        }
        if (l16 == 0) {
            floatx4 u0 = {c[0], c[1], c[2], c[3]};
            floatx4 u1 = {c[4], c[5], c[6], c[7]};
            *(floatx4*)(ctxF + w * 256 + kkt * 32 + quad * 8)     = u0;
            *(floatx4*)(ctxF + w * 256 + kkt * 32 + quad * 8 + 4) = u1;
        }
    }
    __syncthreads();

    int cidx = b * NCHUNK + chunk;
    {
        float cx = 0.f;
#pragma unroll
        for (int w2 = 0; w2 < 4; ++w2) cx += ctxF[w2 * 256 + t];
        ctx_ws[(size_t)cidx * ENC + t] = cx;
    }
    if (t == 0) {
        ml_ws[cidx * 2]     = m;
        ml_ws[cidx * 2 + 1] = l;
    }
}

// Kernel 3: combine chunk partials per batch; finalize context and attn.
// 8 blocks per batch: each redundantly computes (m,L); block j==0 emits context;
// each block normalizes a 512-element attn slice.
__global__ void final_kernel(const float* __restrict__ ctx_ws,
                             const float* __restrict__ ml_ws,
                             float* __restrict__ out) {
    int blk = blockIdx.x, b = blk >> 3, j = blk & 7;
    int t = threadIdx.x;
    float m = -3.4e38f;
    for (int c = 0; c < NCHUNK; ++c)
        m = fmaxf(m, ml_ws[(b * NCHUNK + c) * 2]);
    float L = 0.f;
    for (int c = 0; c < NCHUNK; ++c)
        L += ml_ws[(b * NCHUNK + c) * 2 + 1] * __expf(ml_ws[(b * NCHUNK + c) * 2] - m);
    float inv = 1.0f / L;

    if (j == 0) {
        float cx = 0.f;
        for (int c = 0; c < NCHUNK; ++c) {
            float sc_c = __expf(ml_ws[(b * NCHUNK + c) * 2] - m);
            cx += sc_c * ctx_ws[(size_t)(b * NCHUNK + c) * ENC + t];
        }
        out[b * ENC + t] = cx * inv;
    }

    size_t base = OUT_ATTN + (size_t)b * SEQ + j * 512;
    float r0 = out[base + t];
    float r1 = out[base + 256 + t];
    out[base + t]       = __expf(r0 - m) * inv;
    out[base + 256 + t] = __expf(r1 - m) * inv;
}

extern "C" void kernel_launch(void* const* d_in, const int* in_sizes, int n_in,
                              void* d_out, int out_size, void* d_ws, size_t ws_size,
                              hipStream_t stream) {
    const float* dh   = (const float*)d_in[0];
    const float* enc  = (const float*)d_in[1];
    const int*   mask = (const int*)d_in[2];
    const float* Wd   = (const float*)d_in[3];
    const float* bd   = (const float*)d_in[4];
    const float* We   = (const float*)d_in[5];
    const float* be   = (const float*)d_in[6];
    const float* Wa   = (const float*)d_in[7];
    const float* ba   = (const float*)d_in[8];
    float* out = (float*)d_out;

    // ws (floats): ctx_ws[64*64*256] | ml_ws[64*64*2] | dpb4[64*4*256] | WeF (bf16, 64K shorts)
    float* w      = (float*)d_ws;
    float* ctx_ws = w;
    float* ml_ws  = w + BATCH * NCHUNK * ENC;
    float* dpb4   = ml_ws + BATCH * NCHUNK * 2;
    short* WeF    = (short*)(dpb4 + BATCH * 4 * ENC);

    hipLaunchKernelGGL(prep_kernel,  dim3(256 + 32),       dim3(256), 0, stream,
                       dh, Wd, bd, be, We, dpb4, WeF);
    hipLaunchKernelGGL(main_kernel,  dim3(BATCH * NCHUNK), dim3(256), 0, stream,
                       enc, mask, WeF, dpb4, Wa, ba, out, ctx_ws, ml_ws);
    hipLaunchKernelGGL(final_kernel, dim3(BATCH * 8),      dim3(256), 0, stream,
                       ctx_ws, ml_ws, out);
}

// Round 5
// 430.704 us; speedup vs baseline: 1.1416x; 1.0276x over previous
//
#include <hip/hip_runtime.h>

#define BATCH 64
#define SEQ   4096
#define DECD  512
#define ENC   256
#define TS    128                // rows per chunk-iteration (8 waves x 16 rows)
#define NCHUNK (SEQ / TS)        // 32 chunks per batch
#define ITERS 8                  // chunks per block (persistent blocks: 256 = 64*4)
#define OUT_ATTN (BATCH * ENC)   // offset of attn region in d_out

typedef short  short8  __attribute__((ext_vector_type(8)));
typedef float  floatx4 __attribute__((ext_vector_type(4)));

__device__ __forceinline__ short f2bf(float f) {
    union { float f; unsigned u; } v; v.f = f;
    unsigned u = v.u;
    u += 0x7FFFu + ((u >> 16) & 1u);
    return (short)(u >> 16);
}

__device__ __forceinline__ float bf2f(short s) {
    union { unsigned u; float f; } v;
    v.u = ((unsigned)(unsigned short)s) << 16;
    return v.f;
}

__device__ __forceinline__ float fast_tanh(float x) {
    x = fminf(fmaxf(x, -9.0f), 9.0f);
    float e2 = __expf(2.0f * x);
    float r  = __builtin_amdgcn_rcpf(e2 + 1.0f);
    return fmaf(-2.0f, r, 1.0f);
}

// async global->LDS, 16B per lane. LDS dest = wave-uniform base + lane*16.
__device__ __forceinline__ void gload_lds16(const short* g, short* l) {
    __builtin_amdgcn_global_load_lds(
        (const __attribute__((address_space(1))) unsigned int*)g,
        (__attribute__((address_space(3))) unsigned int*)l,
        16, 0, 0);
}

// Kernel 1 (merged): blocks [0,256): dp split-K x4; blocks [256,288): pack We.
__global__ void prep_kernel(const float* __restrict__ dh,
                            const float* __restrict__ Wd,
                            const float* __restrict__ bd,
                            const float* __restrict__ be,
                            const float* __restrict__ We,
                            float* __restrict__ dpb4,
                            short* __restrict__ WeF) {
    __shared__ float dhs[128];
    int blk = blockIdx.x;
    int t = threadIdx.x;
    if (blk < 256) {
        // dpb4[(b*4+j)][e] = partial sum (+ bd+be on j==0)
        int b = blk >> 2, j = blk & 3;
        if (t < 128) dhs[t] = dh[b * DECD + j * 128 + t];
        __syncthreads();
        const float* wp = Wd + (size_t)(j * 128) * ENC + t;
        float a0 = 0.f, a1 = 0.f, a2 = 0.f, a3 = 0.f;
#pragma unroll 4
        for (int d = 0; d < 128; d += 4) {
            a0 = fmaf(dhs[d],     wp[(size_t)(d)     * ENC], a0);
            a1 = fmaf(dhs[d + 1], wp[(size_t)(d + 1) * ENC], a1);
            a2 = fmaf(dhs[d + 2], wp[(size_t)(d + 2) * ENC], a2);
            a3 = fmaf(dhs[d + 3], wp[(size_t)(d + 3) * ENC], a3);
        }
        float r = (a0 + a1) + (a2 + a3);
        if (j == 0) r += bd[t] + be[t];
        dpb4[(size_t)(b * 4 + j) * ENC + t] = r;
    } else {
        // pack We into bf16 MFMA B-fragment layout; each kt slice = 16KB contiguous
        int gid  = (blk - 256) * 256 + t;            // 0..8191
        int lane = gid & 63;
        int nt   = (gid >> 6) & 15;
        int kt   = gid >> 10;
        int quad = lane >> 4, l16 = lane & 15;
        int n = nt * 16 + l16;
        short8 v;
#pragma unroll
        for (int j = 0; j < 8; ++j) {
            int k = kt * 32 + quad * 8 + j;
            v[j] = f2bf(We[k * ENC + n]);
        }
        *(short8*)(WeF + gid * 8) = v;
    }
}

// Kernel 2 (main): 256 persistent blocks (1 per CU, 8 waves each).
// Full WeF (128 KB) staged into LDS ONCE per block; each block then loops over
// ITERS=8 chunks of 128 rows with no B re-staging. A-tile for chunk i+1 is
// prefetched into registers (pf, 64 VGPRs) while chunk i computes. enc is read
// exactly once; context comes from the live bf16 A-fragments (shfl reduce).
__global__ __launch_bounds__(512, 2) void main_kernel(
    const float* __restrict__ enc, const int* __restrict__ mask,
    const short* __restrict__ WeF, const float* __restrict__ dpb4,
    const float* __restrict__ Wa, const float* __restrict__ ba,
    float* __restrict__ out, float* __restrict__ ctx_ws, float* __restrict__ ml_ws)
{
    __shared__ short Bs[65536];          // full WeF, 128 KB, resident all kernel
    __shared__ float scF[TS];            // scores        (epilogue scratch, 128)
    __shared__ float wgtF[TS];           // weights       (128)
    __shared__ float dpbF[ENC];          // dpb           (256)
    __shared__ float waF[ENC];           // Wa            (256)
    __shared__ float ctxF[8 * ENC];      // per-wave ctx partials [8][256]

    int blk    = blockIdx.x;             // 0..255
    int b      = blk >> 2;               // 4 blocks per batch
    int chunk0 = (blk & 3) * ITERS;      // 8 consecutive chunks each
    int t    = threadIdx.x;
    int w    = t >> 6, lane = t & 63;
    int quad = lane >> 4, l16 = lane & 15;

    const float* encB  = enc + (size_t)b * SEQ * ENC;
    const float* aRow0 = encB + (size_t)(chunk0 * TS + w * 16 + l16) * ENC + quad * 8;

    // ---- stage full WeF into LDS: 16 rounds x 512 threads x 16B = 128 KB ----
#pragma unroll
    for (int j = 0; j < 16; ++j) {
        int off = j * 4096 + w * 512 + lane * 8;   // shorts; wave-uniform base + lane*16B
        gload_lds16(WeF + off, Bs + off);
    }

    // epilogue constants into LDS scratch (iteration-invariant: b fixed per block)
    if (t < 256) {
        const float* dp = dpb4 + (size_t)b * 4 * ENC;
        dpbF[t] = dp[t] + dp[ENC + t] + dp[2 * ENC + t] + dp[3 * ENC + t];
    } else {
        waF[t - 256] = Wa[t - 256];
    }
    float ba0 = ba[0];

    // ---- prefetch A for it=0 (16 x dwordx4 per thread = 64 floats) ----
    floatx4 pf[16];
#pragma unroll
    for (int q = 0; q < 8; ++q) {
        pf[2 * q]     = *(const floatx4*)(aRow0 + q * 32);
        pf[2 * q + 1] = *(const floatx4*)(aRow0 + q * 32 + 4);
    }

    __syncthreads();   // drains vmcnt: WeF staged, scratch ready

    for (int it = 0; it < ITERS; ++it) {
        int chunk  = chunk0 + it;
        int s_base = chunk * TS;

        // convert prefetched f32 -> bf16 A-fragments (kept live through ctx pass)
        short8 af[8];
#pragma unroll
        for (int kkt = 0; kkt < 8; ++kkt) {
            short8 a;
#pragma unroll
            for (int j = 0; j < 4; ++j) {
                a[j]     = f2bf(pf[2 * kkt][j]);
                a[j + 4] = f2bf(pf[2 * kkt + 1][j]);
            }
            af[kkt] = a;
        }

        // issue next-iteration A loads now; they complete under MFMA + epilogue
        if (it + 1 < ITERS) {
            const float* aN = aRow0 + (size_t)(it + 1) * TS * ENC;
#pragma unroll
            for (int q = 0; q < 8; ++q) {
                pf[2 * q]     = *(const floatx4*)(aN + q * 32);
                pf[2 * q + 1] = *(const floatx4*)(aN + q * 32 + 4);
            }
        }

        floatx4 acc[16];
#pragma unroll
        for (int nt = 0; nt < 16; ++nt) acc[nt] = (floatx4){0.f, 0.f, 0.f, 0.f};

#pragma unroll
        for (int kkt = 0; kkt < 8; ++kkt) {
            const short* bp = Bs + kkt * 8192 + lane * 8;
#pragma unroll
            for (int ng = 0; ng < 4; ++ng) {
                short8 bf0 = *(const short8*)(bp + (ng * 4 + 0) * 512);
                short8 bf1 = *(const short8*)(bp + (ng * 4 + 1) * 512);
                short8 bf2 = *(const short8*)(bp + (ng * 4 + 2) * 512);
                short8 bf3 = *(const short8*)(bp + (ng * 4 + 3) * 512);
                acc[ng * 4 + 0] = __builtin_amdgcn_mfma_f32_16x16x32_bf16(af[kkt], bf0, acc[ng * 4 + 0], 0, 0, 0);
                acc[ng * 4 + 1] = __builtin_amdgcn_mfma_f32_16x16x32_bf16(af[kkt], bf1, acc[ng * 4 + 1], 0, 0, 0);
                acc[ng * 4 + 2] = __builtin_amdgcn_mfma_f32_16x16x32_bf16(af[kkt], bf2, acc[ng * 4 + 2], 0, 0, 0);
                acc[ng * 4 + 3] = __builtin_amdgcn_mfma_f32_16x16x32_bf16(af[kkt], bf3, acc[ng * 4 + 3], 0, 0, 0);
            }
        }

        // score_row = ba + sum_n Wa[n]*tanh(P[row][n] + dpb[n])
        float part[4] = {0.f, 0.f, 0.f, 0.f};
#pragma unroll
        for (int nt = 0; nt < 16; ++nt) {
            int n = nt * 16 + l16;
            float wa  = waF[n];
            float dpv = dpbF[n];
#pragma unroll
            for (int r = 0; r < 4; ++r)
                part[r] = fmaf(wa, fast_tanh(acc[nt][r] + dpv), part[r]);
        }
#pragma unroll
        for (int r = 0; r < 4; ++r) {
            float v = part[r];
            v += __shfl_xor(v, 1);
            v += __shfl_xor(v, 2);
            v += __shfl_xor(v, 4);
            v += __shfl_xor(v, 8);
            part[r] = v;
        }
        if (l16 == 0) {
            int idx0 = w * 16 + quad * 4;
            int s0 = s_base + idx0;
            const int4 mv = *(const int4*)(mask + b * SEQ + s0);
            int mvals[4] = {mv.x, mv.y, mv.z, mv.w};
#pragma unroll
            for (int r = 0; r < 4; ++r) {
                float scv = part[r] + ba0;
                if (mvals[r] == 0) scv = -1e10f;
                scF[idx0 + r] = scv;
                out[OUT_ATTN + (size_t)b * SEQ + s0 + r] = scv;   // raw; final normalizes
            }
        }
        __syncthreads();

        // chunk softmax over 128 scores (each wave redundantly, via shuffles)
        float v0 = scF[lane], v1 = scF[lane + 64];
        float m = fmaxf(v0, v1);
        m = fmaxf(m, __shfl_xor(m, 1));
        m = fmaxf(m, __shfl_xor(m, 2));
        m = fmaxf(m, __shfl_xor(m, 4));
        m = fmaxf(m, __shfl_xor(m, 8));
        m = fmaxf(m, __shfl_xor(m, 16));
        m = fmaxf(m, __shfl_xor(m, 32));
        float e0 = __expf(v0 - m), e1 = __expf(v1 - m);
        float l = e0 + e1;
        l += __shfl_xor(l, 1);
        l += __shfl_xor(l, 2);
        l += __shfl_xor(l, 4);
        l += __shfl_xor(l, 8);
        l += __shfl_xor(l, 16);
        l += __shfl_xor(l, 32);
        if (t < TS) wgtF[t] = __expf(scF[t] - m);
        __syncthreads();

        // context partial from the live bf16 A-fragments (no second enc read)
        float wrow = wgtF[w * 16 + l16];
#pragma unroll
        for (int kkt = 0; kkt < 8; ++kkt) {
            float c[8];
#pragma unroll
            for (int j = 0; j < 8; ++j)
                c[j] = wrow * bf2f(af[kkt][j]);
#pragma unroll
            for (int j = 0; j < 8; ++j) {
                c[j] += __shfl_xor(c[j], 1);
                c[j] += __shfl_xor(c[j], 2);
                c[j] += __shfl_xor(c[j], 4);
                c[j] += __shfl_xor(c[j], 8);
            }
            if (l16 == 0) {
                floatx4 u0 = {c[0], c[1], c[2], c[3]};
                floatx4 u1 = {c[4], c[5], c[6], c[7]};
                *(floatx4*)(ctxF + w * 256 + kkt * 32 + quad * 8)     = u0;
                *(floatx4*)(ctxF + w * 256 + kkt * 32 + quad * 8 + 4) = u1;
            }
        }
        __syncthreads();

        int cidx = b * NCHUNK + chunk;
        if (t < 256) {
            float cx = 0.f;
#pragma unroll
            for (int w2 = 0; w2 < 8; ++w2) cx += ctxF[w2 * 256 + t];
            ctx_ws[(size_t)cidx * ENC + t] = cx;
        }
        if (t == 0) {
            ml_ws[cidx * 2]     = m;
            ml_ws[cidx * 2 + 1] = l;
        }
        // no trailing barrier needed: next iteration's first scratch write (scF)
        // is separated from this iteration's scF/wgtF/ctxF reads by >=2 barriers.
    }
}

// Kernel 3: combine chunk partials per batch; finalize context and attn.
// 8 blocks per batch: each redundantly computes (m,L); block j==0 emits context;
// each block normalizes a 512-element attn slice.
__global__ void final_kernel(const float* __restrict__ ctx_ws,
                             const float* __restrict__ ml_ws,
                             float* __restrict__ out) {
    int blk = blockIdx.x, b = blk >> 3, j = blk & 7;
    int t = threadIdx.x;
    float m = -3.4e38f;
    for (int c = 0; c < NCHUNK; ++c)
        m = fmaxf(m, ml_ws[(b * NCHUNK + c) * 2]);
    float L = 0.f;
    for (int c = 0; c < NCHUNK; ++c)
        L += ml_ws[(b * NCHUNK + c) * 2 + 1] * __expf(ml_ws[(b * NCHUNK + c) * 2] - m);
    float inv = 1.0f / L;

    if (j == 0) {
        float cx = 0.f;
        for (int c = 0; c < NCHUNK; ++c) {
            float sc_c = __expf(ml_ws[(b * NCHUNK + c) * 2] - m);
            cx += sc_c * ctx_ws[(size_t)(b * NCHUNK + c) * ENC + t];
        }
        out[b * ENC + t] = cx * inv;
    }

    size_t base = OUT_ATTN + (size_t)b * SEQ + j * 512;
    float r0 = out[base + t];
    float r1 = out[base + 256 + t];
    out[base + t]       = __expf(r0 - m) * inv;
    out[base + 256 + t] = __expf(r1 - m) * inv;
}

extern "C" void kernel_launch(void* const* d_in, const int* in_sizes, int n_in,
                              void* d_out, int out_size, void* d_ws, size_t ws_size,
                              hipStream_t stream) {
    const float* dh   = (const float*)d_in[0];
    const float* enc  = (const float*)d_in[1];
    const int*   mask = (const int*)d_in[2];
    const float* Wd   = (const float*)d_in[3];
    const float* bd   = (const float*)d_in[4];
    const float* We   = (const float*)d_in[5];
    const float* be   = (const float*)d_in[6];
    const float* Wa   = (const float*)d_in[7];
    const float* ba   = (const float*)d_in[8];
    float* out = (float*)d_out;

    // ws (floats): ctx_ws[64*32*256] | ml_ws[64*32*2] | dpb4[64*4*256] | WeF (bf16, 64K shorts)
    float* w      = (float*)d_ws;
    float* ctx_ws = w;
    float* ml_ws  = w + BATCH * NCHUNK * 2 * ENC;
    // NOTE: ml_ws offset uses the round-0 (larger) ctx_ws stride for safety; the
    // regions below never overlap ctx_ws[64*32*256] actually used.
    ml_ws  = w + BATCH * NCHUNK * ENC;
    float* dpb4   = ml_ws + BATCH * NCHUNK * 2;
    short* WeF    = (short*)(dpb4 + BATCH * 4 * ENC);

    hipLaunchKernelGGL(prep_kernel,  dim3(256 + 32), dim3(256), 0, stream,
                       dh, Wd, bd, be, We, dpb4, WeF);
    hipLaunchKernelGGL(main_kernel,  dim3(256),      dim3(512), 0, stream,
                       enc, mask, WeF, dpb4, Wa, ba, out, ctx_ws, ml_ws);
    hipLaunchKernelGGL(final_kernel, dim3(BATCH * 8), dim3(256), 0, stream,
                       ctx_ws, ml_ws, out);
}